// Round 3
// baseline (3080.626 us; speedup 1.0000x reference)
//
#include <hip/hip_runtime.h>

typedef unsigned short u16;
typedef unsigned int   u32;
typedef __attribute__((ext_vector_type(8))) short short8;  // 8 bf16 (4 VGPRs) MFMA frag
typedef __attribute__((ext_vector_type(4))) float f32x4;   // MFMA 16x16 accumulator

#define B_   16
#define S_   128
#define H_   1024
#define E_   512
#define V_   32000

static __device__ __forceinline__ float bf2f(u16 x){
  u32 u = ((u32)x) << 16; float f; __builtin_memcpy(&f, &u, 4); return f;
}
static __device__ __forceinline__ u16 f2bf(float f){
  u32 u; __builtin_memcpy(&u, &f, 4);
  u += 0x7fffu + ((u >> 16) & 1u);           // round-to-nearest-even
  return (u16)(u >> 16);
}
static __device__ __forceinline__ void gl2lds16(const void* g, void* l){
  // async global->LDS, 16B/lane; LDS dest = wave-uniform base + lane*16
  __builtin_amdgcn_global_load_lds((const __attribute__((address_space(1))) u32*)g,
                                   (__attribute__((address_space(3))) u32*)l, 16, 0, 0);
}
static __device__ __forceinline__ float sigm(float x){ return 1.0f/(1.0f + __expf(-x)); }
static __device__ __forceinline__ float tanh_f(float x){
  float a = fabsf(x);
  float e = __expf(-2.0f*a);
  float r = (1.0f - e)/(1.0f + e);           // e<=1 always: no inf/NaN
  return x < 0.0f ? -r : r;
}
// dtype-agnostic scalar load (element index i)
static __device__ __forceinline__ float ldf(const void* base, long i, int is32){
  return is32 ? ((const float*)base)[i] : bf2f(((const u16*)base)[i]);
}
// dtype-agnostic 8-element load -> packed bf16 (i must be 8-aligned)
static __device__ __forceinline__ short8 load8(const void* base, long i, int is32){
  short8 r;
  if (is32){
    const float* p = (const float*)base + i;
    f32x4 a = *(const f32x4*)p;
    f32x4 b = *(const f32x4*)(p + 4);
    r[0]=(short)f2bf(a[0]); r[1]=(short)f2bf(a[1]);
    r[2]=(short)f2bf(a[2]); r[3]=(short)f2bf(a[3]);
    r[4]=(short)f2bf(b[0]); r[5]=(short)f2bf(b[1]);
    r[6]=(short)f2bf(b[2]); r[7]=(short)f2bf(b[3]);
  } else {
    r = *(const short8*)((const u16*)base + i);
  }
  return r;
}

// ---------------------------------------------------------------------------
// dtype sniff on h ~ N(0,1): for bf16 data, every u32's bits[7:14] are a bf16
// exponent field (in [100,140] essentially always); for fp32 data they are
// uniform mantissa bits (~16% in range). 1024 words, majority vote.
// ---------------------------------------------------------------------------
__global__ void k_detect(const u32* __restrict__ h32, u32* __restrict__ flag){
  const int lane = threadIdx.x;        // 64
  int cnt = 0;
  for (int i = 0; i < 16; ++i){
    u32 w = h32[lane*16 + i];
    u32 e = (w >> 7) & 0xFFu;
    cnt += (e >= 100u && e <= 140u) ? 1 : 0;
  }
  for (int off = 32; off; off >>= 1) cnt += __shfl_down(cnt, off, 64);
  if (lane == 0) flag[0] = (cnt < 512) ? 1u : 0u;   // 1 = fp32 inputs/outputs
}

// ---------------------------------------------------------------------------
// init: h_buf parity 0 = (hi,lo) of h0; c_f32 = c0
// h_buf layout: [parity 2][hi/lo 2][B][H] bf16
// ---------------------------------------------------------------------------
__global__ void k_init(const void* __restrict__ h_in, const void* __restrict__ c_in,
                       u16* __restrict__ h_buf, float* __restrict__ c_f32,
                       const u32* __restrict__ flag){
  const int is32 = (int)flag[0];
  const int tid = threadIdx.x;
  for (int i = tid; i < B_*H_; i += 256){
    float hv = ldf(h_in, i, is32);
    u16 hi = f2bf(hv);
    h_buf[i]          = hi;
    h_buf[B_*H_ + i]  = f2bf(hv - bf2f(hi));
    c_f32[i]          = ldf(c_in, i, is32);
  }
}

// ---------------------------------------------------------------------------
// Phase A: xg[t][q][r][b] (fp32) = emb[tgt[b][t]] . W_ih[g=q*1024+r] + b_ih + b_hh
// M-tile 64 tokens (token m = t*16+b), N-tile 64 gates, K=512, BK=32.
// Plain LDS staging (dtype-generic via load8).
// ---------------------------------------------------------------------------
__global__ __launch_bounds__(256) void k_xg(
    const int* __restrict__ tgt, const void* __restrict__ emb,
    const void* __restrict__ W_ih, const void* __restrict__ b_ih,
    const void* __restrict__ b_hh, float* __restrict__ xg,
    const u32* __restrict__ flag)
{
  const int is32 = (int)flag[0];
  __shared__ __align__(16) u16 la[64*32];
  __shared__ __align__(16) u16 lb[64*32];
  __shared__ int ids[64];
  const int nb = blockIdx.x;           // gate block   (64)
  const int mb = blockIdx.y;           // token block  (32)
  const int tid = threadIdx.x, lane = tid & 63, wv = tid >> 6;
  const int wm = wv >> 1, wn = wv & 1; // 2x2 wave grid, wave tile 32x32
  const int g0 = nb*64;

  if (tid < 64){
    int m = mb*64 + tid;               // token; t = m>>4, b = m&15; tgt is [B][S]
    ids[tid] = tgt[(m & 15)*S_ + (m >> 4)];
  }
  __syncthreads();

  f32x4 acc[2][2];
#pragma unroll
  for (int i = 0; i < 2; ++i)
#pragma unroll
    for (int j = 0; j < 2; ++j) acc[i][j] = (f32x4){0.f,0.f,0.f,0.f};

  const int srow = tid >> 2, sk = (tid & 3)*8;   // 64 rows x 4 loaders of 8
  const long arow = (long)ids[srow]*E_ + sk;
  const long brow = (long)(g0 + srow)*E_ + sk;

  for (int k0 = 0; k0 < E_; k0 += 32){
    short8 va = load8(emb,  arow + k0, is32);
    short8 vb = load8(W_ih, brow + k0, is32);
    *(short8*)&la[srow*32 + sk] = va;
    *(short8*)&lb[srow*32 + sk] = vb;
    __syncthreads();
    short8 af[2], bfv[2];
#pragma unroll
    for (int mt = 0; mt < 2; ++mt)
      af[mt] = *(const short8*)&la[(wm*32 + mt*16 + (lane & 15))*32 + ((lane >> 4)*8)];
#pragma unroll
    for (int nt = 0; nt < 2; ++nt)
      bfv[nt] = *(const short8*)&lb[(wn*32 + nt*16 + (lane & 15))*32 + ((lane >> 4)*8)];
#pragma unroll
    for (int mt = 0; mt < 2; ++mt)
#pragma unroll
      for (int nt = 0; nt < 2; ++nt)
        acc[mt][nt] = __builtin_amdgcn_mfma_f32_16x16x32_bf16(af[mt], bfv[nt], acc[mt][nt], 0,0,0);
    __syncthreads();
  }

  // epilogue: C rows = token-in-tile (batch within), cols = gate
  const int col = lane & 15, quad = lane >> 4;
#pragma unroll
  for (int nt = 0; nt < 2; ++nt){
    int g = g0 + wn*32 + nt*16 + col;
    float bias = ldf(b_ih, g, is32) + ldf(b_hh, g, is32);
    int q = g >> 10, r = g & 1023;
#pragma unroll
    for (int mt = 0; mt < 2; ++mt){
      int t = mb*4 + wm*2 + mt;
      f32x4 v;
      v[0] = acc[mt][nt][0] + bias;
      v[1] = acc[mt][nt][1] + bias;
      v[2] = acc[mt][nt][2] + bias;
      v[3] = acc[mt][nt][3] + bias;
      *(f32x4*)(xg + ((long)((t*4 + q)*1024 + r)*16 + quad*4)) = v;
    }
  }
}

// ---------------------------------------------------------------------------
// Phase B: one dispatch per timestep. 64 WGs; WG s owns hidden units
// [s*16,s*16+16) for all batches. Reads h_buf parity (t&1), writes ((t+1)&1).
// ---------------------------------------------------------------------------
__global__ __launch_bounds__(256) void k_step(
    const void* __restrict__ W_hh, const float* __restrict__ xg,
    u16* __restrict__ h_buf, float* __restrict__ c_f32,
    u16* __restrict__ hs, const u32* __restrict__ flag, int t)
{
  const int is32 = (int)flag[0];
  const int s    = blockIdx.x;
  const int tid  = threadIdx.x;
  const int lane = tid & 63;
  const int wv   = tid >> 6;           // wave -> K slice [wv*256, wv*256+256)

  __shared__ __align__(16) float part[4][4][16][20];  // [wave][gate][r][b pad20]

  // B-operand fragments: rows q*1024 + s*16 + (lane&15), k = wv*256 + quad*8 + j*32 + i
  short8 wf[4][8];
#pragma unroll
  for (int q = 0; q < 4; ++q){
    const long wrow = (long)(q*H_ + s*16 + (lane & 15))*H_ + wv*256 + ((lane >> 4)*8);
#pragma unroll
    for (int j = 0; j < 8; ++j)
      wf[q][j] = load8(W_hh, wrow + j*32, is32);
  }

  // A = h (hi+lo bf16): A[m = lane&15 = batch][k = hidden]
  f32x4 acc[4];
#pragma unroll
  for (int q = 0; q < 4; ++q) acc[q] = (f32x4){0.f,0.f,0.f,0.f};
  const u16* hp = h_buf + (t & 1)*(2*B_*H_) + (lane & 15)*H_ + wv*256 + ((lane >> 4)*8);
#pragma unroll
  for (int j = 0; j < 8; ++j){
    short8 ahi = *(const short8*)(hp + j*32);
    short8 alo = *(const short8*)(hp + B_*H_ + j*32);
#pragma unroll
    for (int q = 0; q < 4; ++q){
      acc[q] = __builtin_amdgcn_mfma_f32_16x16x32_bf16(ahi, wf[q][j], acc[q], 0,0,0);
      acc[q] = __builtin_amdgcn_mfma_f32_16x16x32_bf16(alo, wf[q][j], acc[q], 0,0,0);
    }
  }
#pragma unroll
  for (int q = 0; q < 4; ++q)
    *(f32x4*)&part[wv][q][lane & 15][(lane >> 4)*4] = acc[q];   // [r][b]
  __syncthreads();

  // epilogue: thread owns (batch eb, hidden s*16+er)
  const int eb = tid >> 4;
  const int er = tid & 15;
  const float* xg_t = xg + (long)t*65536 + (s*16 + er)*16 + eb;  // + q*16384
  float pre0 = xg_t[0], pre1 = xg_t[16384], pre2 = xg_t[32768], pre3 = xg_t[49152];
#pragma unroll
  for (int w = 0; w < 4; ++w){
    pre0 += part[w][0][er][eb];
    pre1 += part[w][1][er][eb];
    pre2 += part[w][2][er][eb];
    pre3 += part[w][3][er][eb];
  }
  const int co = eb*H_ + s*16 + er;
  float c_val = c_f32[co];
  float iv = sigm(pre0), fv = sigm(pre1), gv = tanh_f(pre2), ov = sigm(pre3);
  c_val = fv*c_val + iv*gv;
  float hv = ov*tanh_f(c_val);
  c_f32[co] = c_val;
  u16 hi = f2bf(hv);
  u16 lo = f2bf(hv - bf2f(hi));        // residual: h error ~2^-17 instead of 2^-9
  const int po = ((t + 1) & 1)*(2*B_*H_);
  h_buf[po + co]          = hi;
  h_buf[po + B_*H_ + co]  = lo;
  hs[(eb*S_ + t)*H_ + s*16 + er] = hi;
}

// ---------------------------------------------------------------------------
// Phase C: logits = hs . W_fc^T + b_fc.  M=2048 (m = b*128+t), N=32000, K=1024.
// A (internal bf16 hs): async gl2lds staging. B (input dtype): load8 staging.
// ---------------------------------------------------------------------------
__global__ __launch_bounds__(256) void k_logits(
    const u16* __restrict__ hs, const void* __restrict__ W_fc,
    const void* __restrict__ b_fc, void* __restrict__ outv,
    const u32* __restrict__ flag)
{
  const int is32 = (int)flag[0];
  __shared__ __align__(16) u16 la[128*32];
  __shared__ __align__(16) u16 lb[128*32];
  const int mb = blockIdx.x;           // 16
  const int nb = blockIdx.y;           // 250
  const int tid = threadIdx.x, lane = tid & 63, wv = tid >> 6;
  const int wm = wv >> 1, wn = wv & 1; // 2x2 wave grid, wave tile 64x64
  const long m0 = (long)mb*128;
  const long n0 = (long)nb*128;

  f32x4 acc[4][4];
#pragma unroll
  for (int i = 0; i < 4; ++i)
#pragma unroll
    for (int j = 0; j < 4; ++j) acc[i][j] = (f32x4){0.f,0.f,0.f,0.f};

  const int srow = lane >> 2, scol = (lane & 3)*8;
  const u16* asrc = hs + (m0 + wv*32 + srow)*H_ + scol;
  u16* lda = &la[wv*32*32];
  const int br = tid >> 2, bk = (tid & 3)*8;     // B rows br and br+64
  const long brow0 = (long)(n0 + br)*H_ + bk;
  const long brow1 = (long)(n0 + br + 64)*H_ + bk;

  for (int k0 = 0; k0 < H_; k0 += 32){
    gl2lds16(asrc + k0,          lda);
    gl2lds16(asrc + 16*H_ + k0,  lda + 16*32);
    *(short8*)&lb[br*32 + bk]        = load8(W_fc, brow0 + k0, is32);
    *(short8*)&lb[(br + 64)*32 + bk] = load8(W_fc, brow1 + k0, is32);
    __syncthreads();
    short8 af[4], bfr[4];
#pragma unroll
    for (int mt = 0; mt < 4; ++mt)
      af[mt] = *(const short8*)&la[(wm*64 + mt*16 + (lane & 15))*32 + ((lane >> 4)*8)];
#pragma unroll
    for (int nt = 0; nt < 4; ++nt)
      bfr[nt] = *(const short8*)&lb[(wn*64 + nt*16 + (lane & 15))*32 + ((lane >> 4)*8)];
#pragma unroll
    for (int mt = 0; mt < 4; ++mt)
#pragma unroll
      for (int nt = 0; nt < 4; ++nt)
        acc[mt][nt] = __builtin_amdgcn_mfma_f32_16x16x32_bf16(af[mt], bfr[nt], acc[mt][nt], 0,0,0);
    __syncthreads();
  }

  const int col = lane & 15, quad = lane >> 4;
#pragma unroll
  for (int nt = 0; nt < 4; ++nt){
    long n = n0 + wn*64 + nt*16 + col;
    float bias = ldf(b_fc, n, is32);
#pragma unroll
    for (int mt = 0; mt < 4; ++mt){
      long m = m0 + wm*64 + mt*16 + quad*4;
      float v0 = acc[mt][nt][0] + bias;
      float v1 = acc[mt][nt][1] + bias;
      float v2 = acc[mt][nt][2] + bias;
      float v3 = acc[mt][nt][3] + bias;
      if (is32){
        float* p = (float*)outv + m*V_ + n;
        p[0] = v0; p[V_] = v1; p[2L*V_] = v2; p[3L*V_] = v3;
      } else {
        u16* p = (u16*)outv + m*V_ + n;
        p[0] = f2bf(v0); p[V_] = f2bf(v1); p[2L*V_] = f2bf(v2); p[3L*V_] = f2bf(v3);
      }
    }
  }
}

// ---------------------------------------------------------------------------
extern "C" void kernel_launch(void* const* d_in, const int* in_sizes, int n_in,
                              void* d_out, int out_size, void* d_ws, size_t ws_size,
                              hipStream_t stream)
{
  (void)in_sizes; (void)n_in; (void)out_size; (void)ws_size;
  const int*  tgt  = (const int*)d_in[0];
  const void* h0   = d_in[1];
  const void* c0   = d_in[2];
  const void* emb  = d_in[3];
  const void* W_ih = d_in[4];
  const void* W_hh = d_in[5];
  const void* b_ih = d_in[6];
  const void* b_hh = d_in[7];
  const void* W_fc = d_in[8];
  const void* b_fc = d_in[9];

  // xg (fp32, 33.5 MB) lives in d_out: dead before k_logits overwrites d_out.
  float* xg = (float*)d_out;
  char* ws    = (char*)d_ws;
  u16*   hs    = (u16*)(ws);             // [16][128][1024] bf16  = 4,194,304 B
  u16*   h_buf = (u16*)(ws + 4194304);   // [2][2][16][1024] bf16 =   131,072 B
  float* c_f32 = (float*)(ws + 4325376); // [16][1024] fp32       =    65,536 B
  u32*   flag  = (u32*)(ws + 4390912);   // [1] u32: 1 = fp32 I/O

  k_detect<<<1, 64, 0, stream>>>((const u32*)h0, flag);
  k_init<<<1, 256, 0, stream>>>(h0, c0, h_buf, c_f32, flag);
  dim3 gA(64, 32);
  k_xg<<<gA, 256, 0, stream>>>(tgt, emb, W_ih, b_ih, b_hh, xg, flag);
  for (int t = 0; t < S_; ++t)
    k_step<<<64, 256, 0, stream>>>(W_hh, xg, h_buf, c_f32, hs, flag, t);
  dim3 gC(16, 250);
  k_logits<<<gC, 256, 0, stream>>>(hs, W_fc, b_fc, d_out, flag);
}